// Round 14
// baseline (250.539 us; speedup 1.0000x reference)
//
#include <hip/hip_runtime.h>
#include <hip/hip_cooperative_groups.h>

#define HID 256
#define NSEQ 1024
#define NH 16
#define DH 4
#define NB 4
#define SCALEF 0.5f
#define HEADSZ (NB * NH * NSEQ * DH)   // 262144 floats per projection buffer

typedef float f4 __attribute__((ext_vector_type(4)));

__device__ __forceinline__ float rfl(float x) {
    return __builtin_bit_cast(float,
        __builtin_amdgcn_readfirstlane(__builtin_bit_cast(int, x)));
}

#define LOG2E 1.44269504f
#define EOFF  (-16.f * LOG2E)

// ---------------------------------------------------------------------------
// One kernel, three phases. phase==-1: cooperative (grid.sync between
// phases). phase>=0: run only that phase (fallback path = 3 normal
// launches, no grid.sync executed). 512 blocks x 256 threads,
// launch_bounds(256,4): needs only 2 blocks/CU co-resident (4 possible:
// 32KB LDS x4 = 128 <= 160KB, VGPR capped 128) -> robust cooperative launch.
// ---------------------------------------------------------------------------
__global__ __launch_bounds__(256, 4) void fused_kernel(
    const float* __restrict__ q, const float* __restrict__ k,
    const float* __restrict__ v, const float* __restrict__ bias,
    const float* __restrict__ Wq, const float* __restrict__ Wk,
    const float* __restrict__ Wv, const float* __restrict__ Wo,
    const float* __restrict__ bo, const float* __restrict__ gamma,
    const float* __restrict__ beta, const float* __restrict__ rmean,
    const float* __restrict__ rvar, float* ws, float* out, int phase)
{
    __shared__ float smem[8192];               // 32 KB, reused across phases
    const int tid  = threadIdx.x;
    const int blk  = blockIdx.x;
    const bool coop = (phase < 0);
    float* x2 = ws + (size_t)3 * HEADSZ;

    // ---------------- P1: projections (192 of 512 blocks) ----------------
    if ((coop || phase == 0) && blk < 192) {
        const int pos0 = (blk & 15) * 64;
        const int p    = (blk >> 4) % 3;
        const int b    = blk / 48;
        const float* in = (p == 0) ? q : (p == 1) ? k : v;
        const float* W  = (p == 0) ? Wq : (p == 1) ? Wk : Wv;
        float* dst = ws + (size_t)p * HEADSZ;

        float (*lds_in)[64] = (float(*)[64])smem;   // 16 KB
        const int pos_l = tid & 63;
        int cb = __builtin_amdgcn_readfirstlane(tid >> 6);
        const int row_l = tid >> 4;
        const int col4  = tid & 15;
        const float* inb = in + (size_t)b * HID * NSEQ + pos0;

        float acc[16];
#pragma unroll
        for (int j = 0; j < 16; ++j) acc[j] = 0.f;

        f4 vbuf[4];
#pragma unroll
        for (int t = 0; t < 4; ++t)
            vbuf[t] = *(const f4*)(inb + (size_t)(row_l + 16 * t) * NSEQ + col4 * 4);

        for (int c = 0; c < 4; ++c) {
#pragma unroll
            for (int t = 0; t < 4; ++t)
                *(f4*)&lds_in[row_l + 16 * t][col4 * 4] = vbuf[t];
            __syncthreads();
            if (c < 3) {
#pragma unroll
                for (int t = 0; t < 4; ++t)
                    vbuf[t] = *(const f4*)(inb +
                        (size_t)((c + 1) * 64 + row_l + 16 * t) * NSEQ + col4 * 4);
            }
#pragma unroll
            for (int i8 = 0; i8 < 64; i8 += 8) {
                float x[8];
#pragma unroll
                for (int j = 0; j < 8; ++j) x[j] = lds_in[i8 + j][pos_l];
#pragma unroll
                for (int kk = 0; kk < 16; ++kk) {
                    const float* wr = W + (cb * 16 + kk) * HID + c * 64 + i8;
#pragma unroll
                    for (int j = 0; j < 8; ++j)
                        acc[kk] = fmaf(wr[j], x[j], acc[kk]);
                }
            }
            __syncthreads();
        }

        const int pos_g = pos0 + pos_l;
        const int hh    = pos_g & 15;
        const int nsub  = pos_g >> 4;
#pragma unroll
        for (int kk = 0; kk < 16; ++kk) {
            int c = cb * 16 + kk;
            int d = c >> 4;
            int n = (c & 15) * 64 + nsub;
            dst[(((size_t)b * NH + hh) * NSEQ + n) * DH + d] = acc[kk];
        }
    }

    if (coop) cooperative_groups::this_grid().sync();

    // ---------------- P2: attention (512 blocks: b, h, 128-row segment) --
    if (coop || phase == 1) {
        const int b    = blk >> 7;
        const int h    = (blk >> 3) & 15;
        const int seg  = blk & 7;
        const int lane = tid & 63;
        const int wave = tid >> 6;

        const float4* Qh = (const float4*)(ws);
        const float4* Kh = (const float4*)(ws + (size_t)1 * HEADSZ);
        const float4* Vh = (const float4*)(ws + (size_t)2 * HEADSZ);
        const int headbase = (b * NH + h) * NSEQ;
        const int mb = lane * 4;

        float4* ldsK = (float4*)smem;          // 16 KB
        float4* ldsV = ldsK + NSEQ;            // 16 KB

        __syncthreads();                       // smem handoff from P1
#pragma unroll
        for (int t = 0; t < 4; ++t) {
            ldsK[tid + 256 * t] = Kh[headbase + tid + 256 * t];
            ldsV[tid + 256 * t] = Vh[headbase + tid + 256 * t];
        }
        __syncthreads();

#pragma unroll 1
        for (int pass = 0; pass < 4; ++pass) {
            const int n0 = seg * 128 + pass * 32 + wave * 8;

            float qx[8], qy[8], qz[8], qw[8];
#pragma unroll
            for (int r = 0; r < 8; ++r) {
                float4 t = Qh[headbase + n0 + r];
                qx[r] = rfl(t.x); qy[r] = rfl(t.y);
                qz[r] = rfl(t.z); qw[r] = rfl(t.w);
            }

            float sum[8];
            float o[8][4];
#pragma unroll
            for (int r = 0; r < 8; ++r) {
                sum[r] = 0.f;
                o[r][0] = o[r][1] = o[r][2] = o[r][3] = 0.f;
            }

            const float* bwave = bias + ((size_t)headbase + n0) * NSEQ + mb;

#pragma unroll 1
            for (int c = 0; c < 4; ++c) {
                float4 kb[4], vb[4];
#pragma unroll
                for (int i = 0; i < 4; ++i) {
                    kb[i] = ldsK[c * 256 + mb + i];
                    vb[i] = ldsV[c * 256 + mb + i];
                }
#pragma unroll
                for (int r = 0; r < 8; ++r) {
                    f4 bb = __builtin_nontemporal_load(
                        (const f4*)(bwave + (size_t)r * NSEQ + c * 256));
#pragma unroll
                    for (int i = 0; i < 4; ++i) {
                        float dot = qx[r] * kb[i].x + qy[r] * kb[i].y +
                                    qz[r] * kb[i].z + qw[r] * kb[i].w;
                        float s = fmaf(dot, SCALEF, bb[i]);
                        float e = exp2f(fmaf(s, LOG2E, EOFF));
                        sum[r] += e;
                        o[r][0] = fmaf(e, vb[i].x, o[r][0]);
                        o[r][1] = fmaf(e, vb[i].y, o[r][1]);
                        o[r][2] = fmaf(e, vb[i].z, o[r][2]);
                        o[r][3] = fmaf(e, vb[i].w, o[r][3]);
                    }
                }
            }

#pragma unroll
            for (int r = 0; r < 8; ++r) {
                float s = sum[r], a0 = o[r][0], a1 = o[r][1],
                      a2 = o[r][2], a3 = o[r][3];
#pragma unroll
                for (int st = 1; st < 64; st <<= 1) {
                    s  += __shfl_xor(s,  st, 64);
                    a0 += __shfl_xor(a0, st, 64);
                    a1 += __shfl_xor(a1, st, 64);
                    a2 += __shfl_xor(a2, st, 64);
                    a3 += __shfl_xor(a3, st, 64);
                }
                float val = (lane == 0) ? a0 : (lane == 1) ? a1
                          : (lane == 2) ? a2 : a3;
                if (lane < 4)
                    x2[((size_t)b * (NH * DH) + h * DH + lane) * NSEQ + n0 + r] =
                        val / s;
            }
        }
    }

    if (coop) cooperative_groups::this_grid().sync();

    // ---------------- P3: out-proj + BN + LeakyReLU (512 blocks x2) ------
    if (coop || phase == 2) {
#pragma unroll 1
        for (int u = blk; u < 1024; u += 512) {
            const int b      = u >> 8;
            const int r      = u & 255;
            const int chquad = r >> 2;
            const int posq   = r & 3;
            const int oc     = chquad * 4 + (tid >> 6);
            const int pos    = posq * 256 + (tid & 63) * 4;

            const float* xb = x2 + (size_t)b * (NH * DH) * NSEQ;
            f4 acc = (f4)(0.f);
#pragma unroll 16
            for (int c = 0; c < NH * DH; ++c) {
                f4 x = *(const f4*)(xb + (size_t)c * NSEQ + pos);
                acc += Wo[oc * (NH * DH) + c] * x;
            }
            float scale = gamma[oc] * rsqrtf(rvar[oc] + 1e-5f);
            f4 y = (acc + (bo[oc] - rmean[oc])) * scale + beta[oc];
            f4 res;
#pragma unroll
            for (int d = 0; d < 4; ++d) {
                float yy = y[d];
                res[d] = (yy > 0.f) ? yy : 0.2f * yy;
            }
            *(f4*)(out + ((size_t)b * HID + oc) * NSEQ + pos) = res;
        }
    }
}

extern "C" void kernel_launch(void* const* d_in, const int* in_sizes, int n_in,
                              void* d_out, int out_size, void* d_ws, size_t ws_size,
                              hipStream_t stream) {
    const float* q     = (const float*)d_in[0];
    const float* k     = (const float*)d_in[1];
    const float* v     = (const float*)d_in[2];
    const float* bias  = (const float*)d_in[3];
    const float* Wq    = (const float*)d_in[4];
    const float* Wk    = (const float*)d_in[5];
    const float* Wv    = (const float*)d_in[6];
    const float* Wo    = (const float*)d_in[7];
    const float* bo    = (const float*)d_in[8];
    const float* gamma = (const float*)d_in[9];
    const float* beta  = (const float*)d_in[10];
    const float* rmean = (const float*)d_in[11];
    const float* rvar  = (const float*)d_in[12];

    float* ws  = (float*)d_ws;
    float* out = (float*)d_out;
    int phase = -1;

    void* args[] = {
        (void*)&q, (void*)&k, (void*)&v, (void*)&bias,
        (void*)&Wq, (void*)&Wk, (void*)&Wv, (void*)&Wo,
        (void*)&bo, (void*)&gamma, (void*)&beta, (void*)&rmean,
        (void*)&rvar, (void*)&ws, (void*)&out, (void*)&phase
    };
    hipError_t e = hipLaunchCooperativeKernel((void*)fused_kernel, dim3(512),
                                              dim3(256), args, 0, stream);
    if (e != hipSuccess) {
        (void)hipGetLastError();               // clear sticky error
        fused_kernel<<<dim3(512), dim3(256), 0, stream>>>(
            q, k, v, bias, Wq, Wk, Wv, Wo, bo, gamma, beta, rmean, rvar,
            ws, out, 0);
        fused_kernel<<<dim3(512), dim3(256), 0, stream>>>(
            q, k, v, bias, Wq, Wk, Wv, Wo, bo, gamma, beta, rmean, rvar,
            ws, out, 1);
        fused_kernel<<<dim3(512), dim3(256), 0, stream>>>(
            q, k, v, bias, Wq, Wk, Wv, Wo, bo, gamma, beta, rmean, rvar,
            ws, out, 2);
    }
}